// Round 1
// baseline (275.315 us; speedup 1.0000x reference)
//
#include <hip/hip_runtime.h>
#include <stdint.h>

#define N_CL    8
#define C_IN    862
#define SEQ     720
#define SEQP    768            // K padded to 12 x 64
#define PRED    336
#define BATCH   64
#define BK      64
#define NCH     (SEQP / BK)    // 12 chunks
#define NT      (PRED / 16)    // 21 n-tiles per channel
#define XBSTRIDE ((size_t)C_IN * SEQ)   // x stride between batches (elements)

typedef __attribute__((ext_vector_type(8))) __bf16 bf16x8;
typedef __attribute__((ext_vector_type(4))) float  floatx4;

__device__ __forceinline__ void async16(const void* g, void* l) {
  __builtin_amdgcn_global_load_lds(
      (__attribute__((address_space(1))) unsigned int*)(uintptr_t)g,
      (__attribute__((address_space(3))) unsigned int*)l,
      16, 0, 0);
}

// ---- Kernel 1: W fp32 [8][336][720] -> bf16 [8][336][768] (zero-padded K) ----
__global__ void wconv_kernel(const float* __restrict__ W, __bf16* __restrict__ Wb) {
  const int row = blockIdx.x;                 // 0 .. 8*336-1
  const float* src = W + (size_t)row * SEQ;
  __bf16* dst = Wb + (size_t)row * SEQP;
  for (int s = threadIdx.x; s < SEQP; s += blockDim.x) {
    float v = (s < SEQ) ? src[s] : 0.0f;
    dst[s] = (__bf16)v;
  }
}

// ---- Kernel 2: per-channel GEMM. Block = 256 thr (4 waves), one channel. ----
// LDS A: 64 rows x 64 fp32 (256 B/row), 16B-granule XOR-swizzled -> 16384 B
// LDS B: 336 rows x 64 bf16 (128 B/row), 16B-granule XOR-swizzled -> 43008 B
#define A_BYTES 16384
#define B_BYTES 43008

__global__ __launch_bounds__(256, 2) void clin_kernel(
    const float* __restrict__ x, const int* __restrict__ clusters,
    const __bf16* __restrict__ Wb, const float* __restrict__ bias,
    float* __restrict__ out) {
  __shared__ __attribute__((aligned(128))) unsigned char smem[A_BYTES + B_BYTES];
  unsigned char* As = smem;
  unsigned char* Bs = smem + A_BYTES;

  const int c    = blockIdx.x;
  const int cl   = clusters[c];
  const int tid  = threadIdx.x;
  const int wave = tid >> 6;
  const int lane = tid & 63;
  const int q    = lane >> 4;     // quad 0..3
  const int ln   = lane & 15;     // lane-in-quad 0..15

  const float*  xc = x  + (size_t)c * SEQ;
  const __bf16* wc = Wb + (size_t)cl * PRED * SEQP;

  floatx4 acc[NT];
#pragma unroll
  for (int t = 0; t < NT; ++t) acc[t] = (floatx4){0.f, 0.f, 0.f, 0.f};

  // staging lane->row/granule decomposition (fixed per thread)
  const int bA_r  = lane >> 4;       // A: 4 rows per 1024B issue
  const int bA_pg = lane & 15;       // A: 16 granules (16B of fp32) per row
  const int bB_r  = lane >> 3;       // B: 8 rows per 1024B issue
  const int bB_pg = lane & 7;        // B: 8 granules (16B of bf16) per row

  for (int chunk = 0; chunk < NCH; ++chunk) {
    const int k0 = chunk * BK;

    // ---- stage B tile: 336 rows x 128 B = 42 issues of 1024 B ----
    for (int i = wave; i < 42; i += 4) {
      int r  = (i << 3) + bB_r;                 // p-row 0..335
      int lg = bB_pg ^ (r & 7);                 // logical granule for this slot
      async16(wc + (size_t)r * SEQP + k0 + (lg << 3), Bs + i * 1024);
    }

    // ---- stage A tile: 64 rows x 256 B = 16 issues of 1024 B ----
    if (k0 + BK <= SEQ) {
      for (int i = wave; i < 16; i += 4) {
        int r  = (i << 2) + bA_r;               // batch row 0..63
        int lg = bA_pg ^ (r & 15);
        async16(xc + (size_t)r * XBSTRIDE + k0 + (lg << 2), As + i * 1024);
      }
    } else {
      // K tail (only last chunk): manual path with zero-fill past s=720
      for (int i = wave; i < 16; i += 4) {
        int r  = (i << 2) + bA_r;
        int lg = bA_pg ^ (r & 15);
        int s  = k0 + (lg << 2);
        floatx4 v = (floatx4){0.f, 0.f, 0.f, 0.f};
        if (s < SEQ) v = *(const floatx4*)(xc + (size_t)r * XBSTRIDE + s);
        *(floatx4*)(As + r * 256 + (bA_pg << 4)) = v;
      }
    }
    __syncthreads();

    // ---- compute: each wave does its 16-row m-strip x 21 n-tiles ----
    const int mrow = (wave << 4) + ln;          // batch row for A-operand
#pragma unroll
    for (int kk = 0; kk < BK; kk += 32) {
      // A fragment: 8 contiguous k as fp32 (2 swizzled 16B granules), cvt->bf16
      int lg0 = (kk >> 2) + (q << 1);           // even logical granule
      floatx4 af0 = *(const floatx4*)(As + mrow * 256 + (((lg0    ) ^ ln) << 4));
      floatx4 af1 = *(const floatx4*)(As + mrow * 256 + (((lg0 + 1) ^ ln) << 4));
      bf16x8 a;
      a[0] = (__bf16)af0[0]; a[1] = (__bf16)af0[1];
      a[2] = (__bf16)af0[2]; a[3] = (__bf16)af0[3];
      a[4] = (__bf16)af1[0]; a[5] = (__bf16)af1[1];
      a[6] = (__bf16)af1[2]; a[7] = (__bf16)af1[3];

      int lgB  = (kk >> 3) + q;                 // 0..7
      int nsw  = ln & 7;
#pragma unroll
      for (int t = 0; t < NT; ++t) {
        int n = (t << 4) + ln;                  // p index; n&7 == ln&7
        bf16x8 b = *(const bf16x8*)(Bs + n * 128 + ((lgB ^ nsw) << 4));
        acc[t] = __builtin_amdgcn_mfma_f32_16x16x32_bf16(a, b, acc[t], 0, 0, 0);
      }
    }
    __syncthreads();
  }

  // ---- epilogue: bias add + store. C/D layout: col=ln, row=q*4+reg ----
  const float* bc = bias + cl * PRED;
#pragma unroll
  for (int t = 0; t < NT; ++t) {
    int p = (t << 4) + ln;
    float bv = bc[p];
#pragma unroll
    for (int r = 0; r < 4; ++r) {
      int brow = (wave << 4) + (q << 2) + r;    // batch index
      out[((size_t)brow * C_IN + c) * PRED + p] = acc[t][r] + bv;
    }
  }
}

extern "C" void kernel_launch(void* const* d_in, const int* in_sizes, int n_in,
                              void* d_out, int out_size, void* d_ws, size_t ws_size,
                              hipStream_t stream) {
  const float* x   = (const float*)d_in[0];
  const int*   cls = (const int*)d_in[1];
  const float* W   = (const float*)d_in[2];
  const float* b   = (const float*)d_in[3];
  float* out = (float*)d_out;
  __bf16* Wb = (__bf16*)d_ws;   // 8*336*768*2 = 4,128,768 B

  hipLaunchKernelGGL(wconv_kernel, dim3(N_CL * PRED), dim3(256), 0, stream, W, Wb);
  hipLaunchKernelGGL(clin_kernel, dim3(C_IN), dim3(256), 0, stream,
                     x, cls, Wb, b, out);
}